// Round 1
// baseline (450.121 us; speedup 1.0000x reference)
//
#include <hip/hip_runtime.h>

// GumbelSlotSelector: B=8192, K=64, D=128, H=64, LOW_BOUND=1, TAU=1.
// One thread per (b,k) row; one wave per b (K=64 == wave width) so the
// ensure-minimum fixup is a ballot + shuffle-argmax, fully fused.

constexpr int D = 128;
constexpr int H = 64;
constexpr int NROWS = 8192 * 64;  // 524288

__global__ __launch_bounds__(256, 4)
void gumbel_slot_kernel(const float* __restrict__ slots,
                        const float* __restrict__ gumbel_u,
                        const float* __restrict__ fix_u,
                        const float* __restrict__ W1,
                        const float* __restrict__ b1,
                        const float* __restrict__ W2,
                        const float* __restrict__ b2,
                        float* __restrict__ out)
{
    // 256 rows x 32-col chunk, row stride 36 words: b128-aligned (36%4==0),
    // read phase banks (4t+d)..+3 over 16-lane phases -> 2-way = free.
    __shared__ float s_lds[256 * 36];
    const int tid = threadIdx.x;
    const int r0  = blockIdx.x * 256;
    const int r   = r0 + tid;

    float acc[H];
#pragma unroll
    for (int j = 0; j < H; ++j) acc[j] = b1[j];

#pragma unroll 1
    for (int c = 0; c < 4; ++c) {
        // stage slots[r0..r0+256, 32c..32c+32) into LDS, coalesced float4
#pragma unroll
        for (int i = 0; i < 8; ++i) {
            const int linear = (i << 8) + tid;     // 0..2047 float4s
            const int row    = linear >> 3;
            const int col4   = (linear & 7) << 2;
            const float4 v = *reinterpret_cast<const float4*>(
                slots + (size_t)(r0 + row) * D + (c << 5) + col4);
            *reinterpret_cast<float4*>(&s_lds[row * 36 + col4]) = v;
        }
        __syncthreads();
        const float* __restrict__ wbase = W1 + (c << 5) * H;  // W1[d][j], row-major
#pragma unroll 1
        for (int d4 = 0; d4 < 8; ++d4) {
            const float4 s4 =
                *reinterpret_cast<const float4*>(&s_lds[tid * 36 + (d4 << 2)]);
            const float sv[4] = {s4.x, s4.y, s4.z, s4.w};
#pragma unroll
            for (int dd = 0; dd < 4; ++dd) {
                const float s = sv[dd];
                // lane-uniform address -> s_load into SGPRs, K$-hot W1
                const float* __restrict__ w = wbase + ((d4 << 2) + dd) * H;
#pragma unroll
                for (int j = 0; j < H; ++j) acc[j] = fmaf(s, w[j], acc[j]);
            }
        }
        __syncthreads();
    }

    // layer 2: logits[2]
    float l0 = b2[0], l1 = b2[1];
#pragma unroll
    for (int j = 0; j < H; ++j) {
        const float h = fmaxf(acc[j], 0.0f);
        l0 = fmaf(h, W2[2 * j + 0], l0);
        l1 = fmaf(h, W2[2 * j + 1], l1);
    }

    // gumbel noise; tau == 1.0 is a no-op; argmax(softmax(z)) == argmax(z)
    const float2 u2 = *reinterpret_cast<const float2*>(gumbel_u + (size_t)r * 2);
    const float lo = 1e-10f, hi = (float)(1.0 - 1e-7);  // match python f64->f32
    const float u0 = fminf(fmaxf(u2.x, lo), hi);
    const float u1 = fminf(fmaxf(u2.y, lo), hi);
    const float g0 = -logf(-logf(u0));
    const float g1 = -logf(-logf(u1));
    const float z0 = l0 + g0, z1 = l1 + g1;
    float dec = (z1 > z0) ? 1.0f : 0.0f;   // tie -> argmax picks idx 0 -> dec 0

    // keep_probs = softmax(logits)[...,1], numerically stable
    const float m  = fmaxf(l0, l1);
    const float e0 = expf(l0 - m), e1 = expf(l1 - m);
    const float keep = e1 / (e0 + e1);

    // ensure-minimum: wave == one b (64 slots). Fires only if none active:
    // activate argmax(fix_u) (stable ties -> lowest index).
    const unsigned long long act = __ballot(dec != 0.0f);
    if (act == 0ull) {
        const int lane = tid & 63;
        float v   = fix_u[r];
        int   idx = lane;
#pragma unroll
        for (int off = 32; off > 0; off >>= 1) {
            const float ov   = __shfl_xor(v, off, 64);
            const int   oidx = __shfl_xor(idx, off, 64);
            if (ov > v || (ov == v && oidx < idx)) { v = ov; idx = oidx; }
        }
        if (lane == idx) dec = 1.0f;
    }

    out[r] = dec;             // decision [B,K]
    out[NROWS + r] = keep;    // keep_probs [B,K]
}

extern "C" void kernel_launch(void* const* d_in, const int* in_sizes, int n_in,
                              void* d_out, int out_size, void* d_ws, size_t ws_size,
                              hipStream_t stream)
{
    const float* slots  = (const float*)d_in[0];
    const float* gumbel = (const float*)d_in[1];
    const float* fixu   = (const float*)d_in[2];
    const float* W1     = (const float*)d_in[3];
    const float* b1     = (const float*)d_in[4];
    const float* W2     = (const float*)d_in[5];
    const float* b2     = (const float*)d_in[6];
    float* out = (float*)d_out;

    gumbel_slot_kernel<<<NROWS / 256, 256, 0, stream>>>(
        slots, gumbel, fixu, W1, b1, W2, b2, out);
}

// Round 2
// 419.252 us; speedup vs baseline: 1.0736x; 1.0736x over previous
//
#include <hip/hip_runtime.h>

// GumbelSlotSelector via MFMA: layer1 (524288x64x128 fp32 GEMM) done as
// 6-term exact 3xbf16-split MFMA (x = b1+b2+b3 truncation split is exact;
// terms >= 2^-16 kept -> fp32-level accuracy). Layer2 + gumbel + ballot
// fixup fused in a per-wave epilogue. Slots stream global->regs directly
// in A-fragment layout (read exactly once); W1 splits live in LDS (j-major,
// XOR-swizzled 16B chunks, conflict-free).

typedef __attribute__((ext_vector_type(8))) short bf16x8;
typedef __attribute__((ext_vector_type(4))) float f32x4;

constexpr int NROWS = 8192 * 64;   // 524288
constexpr int D = 128, H = 64;

__device__ __forceinline__ void split3(float x, unsigned& h1, unsigned& h2, unsigned& h3) {
    unsigned ux = __float_as_uint(x);
    h1 = ux & 0xFFFF0000u;                       // top 8 mantissa bits
    float r = x - __uint_as_float(h1);           // exact
    h2 = __float_as_uint(r) & 0xFFFF0000u;       // next 8
    float r2 = r - __uint_as_float(h2);          // exact
    h3 = __float_as_uint(r2) & 0xFFFF0000u;      // remaining bits (exact)
}

__global__ __launch_bounds__(512, 2)
void gumbel_slot_mfma(const float* __restrict__ slots,
                      const float* __restrict__ gumbel_u,
                      const float* __restrict__ fix_u,
                      const float* __restrict__ W1,
                      const float* __restrict__ b1,
                      const float* __restrict__ W2,
                      const float* __restrict__ b2,
                      float* __restrict__ out)
{
    // LDS: W1 3-split bf16, j-major [split][j=64][d=128], 16B chunks XOR-swizzled
    // by (j&15); plus epilogue transpose scratch. Total exactly 64 KB.
    __shared__ __align__(16) unsigned short wt[3 * 64 * 128];  // 48 KB
    __shared__ __align__(16) float red[8][16][16][2];          // 16 KB

    const int tid  = threadIdx.x;
    const int wv   = tid >> 6;        // wave 0..7
    const int lane = tid & 63;
    const int quad = lane >> 4;       // 0..3
    const int col  = lane & 15;       // 0..15

    // ---- one-time: split W1 into 3 bf16 planes, transposed [j][d] ----
#pragma unroll
    for (int i = 0; i < 16; ++i) {
        const int e = i * 512 + tid;          // 8192 elements, coalesced
        const int d = e >> 6, j = e & 63;
        unsigned h1, h2, h3;
        split3(W1[e], h1, h2, h3);
        const int chunk = (d >> 3) ^ (j & 15);           // 16B-chunk swizzle
        const int idx = j * 128 + chunk * 8 + (d & 7);
        wt[idx]             = (unsigned short)(h1 >> 16);
        wt[idx + 8192]      = (unsigned short)(h2 >> 16);
        wt[idx + 16384]     = (unsigned short)(h3 >> 16);
    }
    __syncthreads();

    // per-lane constants (same for all tiles)
    float  b1v[4];
    float2 w2v[4];
#pragma unroll
    for (int nt = 0; nt < 4; ++nt) {
        b1v[nt] = b1[nt * 16 + col];
        w2v[nt] = *(const float2*)(W2 + (size_t)(nt * 16 + col) * 2);
    }
    const float2 b2v = *(const float2*)b2;

#pragma unroll 1
    for (int t = 0; t < 2; ++t) {
        const int tile = blockIdx.x + t * 512;           // 1024 tiles of 512 rows
        const int rowW = tile * 512 + wv * 64;           // this wave's 64 rows
        const int r    = rowW + lane;

        f32x4 acc[4][4];
#pragma unroll
        for (int mt = 0; mt < 4; ++mt)
#pragma unroll
            for (int nt = 0; nt < 4; ++nt)
                acc[mt][nt] = f32x4{b1v[nt], b1v[nt], b1v[nt], b1v[nt]};

#pragma unroll 1
        for (int ks = 0; ks < 4; ++ks) {                 // k0 = ks*32
            bf16x8 a1[4], a2[4], a3[4];
#pragma unroll
            for (int mt = 0; mt < 4; ++mt) {
                const float* arow = slots + (size_t)(rowW + mt * 16 + col) * D
                                          + ks * 32 + quad * 8;
                const float4 x0 = *(const float4*)arow;
                const float4 x1 = *(const float4*)(arow + 4);
                const float xs[8] = {x0.x, x0.y, x0.z, x0.w, x1.x, x1.y, x1.z, x1.w};
                union { int i[4]; bf16x8 v; } u1, u2, u3;
#pragma unroll
                for (int p = 0; p < 4; ++p) {
                    unsigned xh1, xh2, xh3, yh1, yh2, yh3;
                    split3(xs[2 * p],     xh1, xh2, xh3);
                    split3(xs[2 * p + 1], yh1, yh2, yh3);
                    u1.i[p] = (int)((xh1 >> 16) | yh1);  // [k even | k odd]
                    u2.i[p] = (int)((xh2 >> 16) | yh2);
                    u3.i[p] = (int)((xh3 >> 16) | yh3);
                }
                a1[mt] = u1.v; a2[mt] = u2.v; a3[mt] = u3.v;
            }
#pragma unroll
            for (int nt = 0; nt < 4; ++nt) {
                const int j = nt * 16 + col;
                const int chunk = (ks * 4 + quad) ^ col;
                const unsigned short* wp = &wt[j * 128 + chunk * 8];
                const bf16x8 bq1 = *(const bf16x8*)(wp);
                const bf16x8 bq2 = *(const bf16x8*)(wp + 8192);
                const bf16x8 bq3 = *(const bf16x8*)(wp + 16384);
#pragma unroll
                for (int mt = 0; mt < 4; ++mt) {
                    f32x4 c = acc[mt][nt];
                    c = __builtin_amdgcn_mfma_f32_16x16x32_bf16(a1[mt], bq1, c, 0, 0, 0);
                    c = __builtin_amdgcn_mfma_f32_16x16x32_bf16(a2[mt], bq1, c, 0, 0, 0);
                    c = __builtin_amdgcn_mfma_f32_16x16x32_bf16(a1[mt], bq2, c, 0, 0, 0);
                    c = __builtin_amdgcn_mfma_f32_16x16x32_bf16(a2[mt], bq2, c, 0, 0, 0);
                    c = __builtin_amdgcn_mfma_f32_16x16x32_bf16(a1[mt], bq3, c, 0, 0, 0);
                    c = __builtin_amdgcn_mfma_f32_16x16x32_bf16(a3[mt], bq1, c, 0, 0, 0);
                    acc[mt][nt] = c;
                }
            }
        }

        // ---- epilogue: layer2 partials + per-row transpose via LDS ----
        // C layout: col(n=j) = lane&15, row = mt*16 + quad*4 + reg.
        float fl0 = 0.f, fl1 = 0.f;
#pragma unroll 1
        for (int mt = 0; mt < 4; ++mt) {
#pragma unroll
            for (int reg = 0; reg < 4; ++reg) {
                float p0 = 0.f, p1 = 0.f;
#pragma unroll
                for (int nt = 0; nt < 4; ++nt) {
                    const float h = fmaxf(acc[mt][nt][reg], 0.f);
                    p0 = fmaf(h, w2v[nt].x, p0);
                    p1 = fmaf(h, w2v[nt].y, p1);
                }
                const int rl = quad * 4 + reg;
                *(float2*)&red[wv][rl][col ^ rl][0] = make_float2(p0, p1);
            }
            __syncthreads();
            if ((lane >> 4) == mt) {
                const int rl = col;           // local row within this mt
                float s0 = 0.f, s1 = 0.f;
#pragma unroll
                for (int c = 0; c < 16; ++c) {
                    const float2 v = *(const float2*)&red[wv][rl][c ^ rl][0];
                    s0 += v.x; s1 += v.y;
                }
                fl0 = s0; fl1 = s1;
            }
            __syncthreads();
        }
        const float l0 = fl0 + b2v.x;
        const float l1 = fl1 + b2v.y;

        // ---- gumbel decision + keep prob ----
        const float2 u2 = *(const float2*)(gumbel_u + (size_t)r * 2);
        const float lo = 1e-10f, hi = (float)(1.0 - 1e-7);
        const float u0 = fminf(fmaxf(u2.x, lo), hi);
        const float u1 = fminf(fmaxf(u2.y, lo), hi);
        const float g0 = -logf(-logf(u0));
        const float g1 = -logf(-logf(u1));
        float dec = ((l1 + g1) > (l0 + g0)) ? 1.0f : 0.0f;

        const float m  = fmaxf(l0, l1);
        const float e0 = expf(l0 - m), e1 = expf(l1 - m);
        const float keep = e1 / (e0 + e1);

        // ensure-minimum: this wave's 64 lanes == one b's 64 slots
        const unsigned long long act = __ballot(dec != 0.0f);
        if (act == 0ull) {
            float v = fix_u[r];
            int  idx = lane;
#pragma unroll
            for (int off = 32; off > 0; off >>= 1) {
                const float ov  = __shfl_xor(v, off, 64);
                const int  oidx = __shfl_xor(idx, off, 64);
                if (ov > v || (ov == v && oidx < idx)) { v = ov; idx = oidx; }
            }
            if (lane == idx) dec = 1.0f;
        }

        out[r] = dec;
        out[NROWS + r] = keep;
    }
}

extern "C" void kernel_launch(void* const* d_in, const int* in_sizes, int n_in,
                              void* d_out, int out_size, void* d_ws, size_t ws_size,
                              hipStream_t stream)
{
    const float* slots  = (const float*)d_in[0];
    const float* gumbel = (const float*)d_in[1];
    const float* fixu   = (const float*)d_in[2];
    const float* W1     = (const float*)d_in[3];
    const float* b1     = (const float*)d_in[4];
    const float* W2     = (const float*)d_in[5];
    const float* b2     = (const float*)d_in[6];
    float* out = (float*)d_out;

    gumbel_slot_mfma<<<512, 512, 0, stream>>>(
        slots, gumbel, fixu, W1, b1, W2, b2, out);
}